// Round 4
// baseline (3810.743 us; speedup 1.0000x reference)
//
#include <hip/hip_runtime.h>

// VGG16-A spiking NN, multi-compartment LIF (K=2), T=3, B=4, fp32.
// Round 4: IC-split across waves within a block + LDS cross-wave reduce.
//  - conv_mid   (layers 1-6): lane = pixel, wave-uniform oc-group (scalar
//    weight loads), NW waves split IC, LDS [NW][OCT][64] reduce, 1 thread
//    per output does LIF. 4-8x more waves than round 3.
//  - conv_small4 (layers 7-12): 4 waves split IC (ic = lane + 64*w), per-wave
//    butterfly transpose-reduce, LDS [4][M] reduce, parallel LIF.

#define BATCH 4

__device__ __forceinline__ float lif_update(float mem_in, float syn, float thr,
                                            float leak, float* mem_out) {
    float m = leak * mem_in + syn;
    float val = 0.f;
    if ((m / thr - 1.f > 0.f) && (1.f - m / (2.f * thr) >= 0.f)) val += 1.f;
    if ((m / (2.f * thr) - 1.f > 0.f) && (1.f - m / (4.f * thr) >= 0.f)) val += 2.f;
    *mem_out = m - thr * val;
    return val;
}

// Element-per-thread conv+LIF (layer 0 only, IC=3).
__global__ void conv_lif_kernel(const float* __restrict__ in,
                                const float* __restrict__ w,
                                float* __restrict__ mem,
                                float* __restrict__ out,
                                const float* __restrict__ thr_v,
                                const float* __restrict__ leak_v,
                                int layer, int IC, int OC, int H, int W, int n) {
    int idx = blockIdx.x * blockDim.x + threadIdx.x;
    if (idx >= n) return;
    int x  = idx % W;
    int y  = (idx / W) % H;
    int oc = (idx / (W * H)) % OC;
    int b  = idx / (W * H * OC);

    const float* wp = w + (size_t)oc * IC * 9;
    const float* ip = in + (size_t)b * IC * H * W;

    float syn = 0.f;
    for (int ic = 0; ic < IC; ++ic) {
        const float* ipc = ip + (size_t)ic * H * W;
        const float* wpc = wp + ic * 9;
#pragma unroll
        for (int ky = 0; ky < 3; ++ky) {
            int yy = y + ky - 1;
            if (yy < 0 || yy >= H) continue;
#pragma unroll
            for (int kx = 0; kx < 3; ++kx) {
                int xx = x + kx - 1;
                if (xx < 0 || xx >= W) continue;
                syn = fmaf(ipc[yy * W + xx], wpc[ky * 3 + kx], syn);
            }
        }
    }
    float mo;
    float val = lif_update(mem[idx], syn, thr_v[layer], leak_v[layer], &mo);
    mem[idx] = mo;
    out[idx] = val;
}

// Layers 1-6. Block = NW waves. blockIdx -> (b, pixel-chunk, oc-group).
// Lane = pixel within 64-pixel chunk. Wave wv accumulates over its IC/NW
// channel chunk into acc[OCT]; LDS reduce across waves; 1 thread/output LIF.
template <int OCT, int NW>
__global__ void conv_mid_kernel(const float* __restrict__ in,
                                const float* __restrict__ w,
                                float* __restrict__ mem,
                                float* __restrict__ out,
                                const float* __restrict__ thr_v,
                                const float* __restrict__ leak_v,
                                int layer, int IC, int OC, int H, int W) {
    int tid = threadIdx.x;
    int lane = tid & 63;
    int wv = tid >> 6;  // 0..NW-1
    int ocg = OC / OCT;
    int HW = H * W;
    int chunks = HW >> 6;
    int bid = blockIdx.x;
    int g  = bid % ocg;
    int ch = (bid / ocg) % chunks;
    int b  = bid / (ocg * chunks);
    int rpw = 64 / W;
    int y = ch * rpw + lane / W;
    int x = lane % W;
    int oc0 = g * OCT;

    int off[9];
    bool msk[9];
#pragma unroll
    for (int ky = 0; ky < 3; ++ky)
#pragma unroll
        for (int kx = 0; kx < 3; ++kx) {
            int yy = y + ky - 1, xx = x + kx - 1;
            bool v = (yy >= 0 && yy < H && xx >= 0 && xx < W);
            msk[ky * 3 + kx] = v;
            off[ky * 3 + kx] = v ? yy * W + xx : 0;
        }

    float acc[OCT];
#pragma unroll
    for (int t = 0; t < OCT; ++t) acc[t] = 0.f;

    const float* ibase = in + (size_t)b * IC * HW;
    const float* wbase = w + (size_t)oc0 * IC * 9;

    int icpw = IC / NW;
    int ic0 = wv * icpw;
#pragma unroll 4
    for (int ic = ic0; ic < ic0 + icpw; ++ic) {
        const float* ip = ibase + (size_t)ic * HW;
        float v[9];
#pragma unroll
        for (int k = 0; k < 9; ++k) v[k] = msk[k] ? ip[off[k]] : 0.f;
        const float* wp = wbase + (size_t)ic * 9;
#pragma unroll
        for (int t = 0; t < OCT; ++t) {
            const float* wt = wp + (size_t)t * IC * 9;
#pragma unroll
            for (int k = 0; k < 9; ++k) acc[t] = fmaf(v[k], wt[k], acc[t]);
        }
    }

    __shared__ float red[NW][OCT][64];
#pragma unroll
    for (int t = 0; t < OCT; ++t) red[wv][t][lane] = acc[t];
    __syncthreads();

    float thr = thr_v[layer], leak = leak_v[layer];
    for (int s = tid; s < OCT * 64; s += NW * 64) {
        int t = s >> 6, p = s & 63;
        float sum = 0.f;
#pragma unroll
        for (int q = 0; q < NW; ++q) sum += red[q][t][p];
        size_t idx = (size_t)(b * OC + oc0 + t) * HW + ch * 64 + p;
        float mo;
        float val = lif_update(mem[idx], sum, thr, leak, &mo);
        mem[idx] = mo;
        out[idx] = val;
    }
}

// Layers 7-12 (4x4 / 2x2 planes). Block = 4 waves, one oc per block.
// ic = lane + 64*wv (+256*pass). Whole S x S plane for all 4 batches in
// registers; per-wave butterfly transpose-reduce; LDS [4][M] cross-wave
// reduce; parallel LIF epilogue.
template <int S>
__global__ void conv_small4_kernel(const float* __restrict__ in,
                                   const float* __restrict__ w,
                                   float* __restrict__ mem,
                                   float* __restrict__ out,
                                   const float* __restrict__ thr_v,
                                   const float* __restrict__ leak_v,
                                   int layer, int IC, int OC) {
    constexpr int SS = S * S;
    constexpr int M = 4 * SS;              // 64 (S=4) or 16 (S=2)
    constexpr int LOG2M = (S == 4) ? 6 : 4;
    int tid = threadIdx.x;
    int lane = tid & 63;
    int wv = tid >> 6;  // 0..3
    int oc = blockIdx.x;

    float acc[M];
#pragma unroll
    for (int i = 0; i < M; ++i) acc[i] = 0.f;

    const float* wrow = w + (size_t)oc * IC * 9;
    for (int ic = lane + (wv << 6); ic < IC; ic += 256) {
        const float* wp = wrow + (size_t)ic * 9;
        float wvv[9];
#pragma unroll
        for (int k = 0; k < 9; ++k) wvv[k] = wp[k];
#pragma unroll
        for (int b = 0; b < 4; ++b) {
            const float4* ip = (const float4*)(in + (size_t)(b * IC + ic) * SS);
            float pv[SS];
#pragma unroll
            for (int q = 0; q < SS / 4; ++q) {
                float4 t4 = ip[q];
                pv[4 * q + 0] = t4.x;
                pv[4 * q + 1] = t4.y;
                pv[4 * q + 2] = t4.z;
                pv[4 * q + 3] = t4.w;
            }
#pragma unroll
            for (int y = 0; y < S; ++y)
#pragma unroll
                for (int x = 0; x < S; ++x) {
                    float a = acc[b * SS + y * S + x];
#pragma unroll
                    for (int ky = 0; ky < 3; ++ky) {
                        int yy = y + ky - 1;
                        if (yy < 0 || yy >= S) continue;
#pragma unroll
                        for (int kx = 0; kx < 3; ++kx) {
                            int xx = x + kx - 1;
                            if (xx < 0 || xx >= S) continue;
                            a = fmaf(pv[yy * S + xx], wvv[ky * 3 + kx], a);
                        }
                    }
                    acc[b * SS + y * S + x] = a;
                }
        }
    }

    // per-wave transpose-reduce: M accs across 64 lanes -> 1 value per lane
#pragma unroll
    for (int step = 0; step < LOG2M; ++step) {
        const int offx = 1 << step;
        const int half = M >> (step + 1);
        const bool hi = (lane & offx) != 0;
#pragma unroll
        for (int i = 0; i < half; ++i) {
            float sent = hi ? acc[i] : acc[i + half];
            float got = __shfl_xor(sent, offx);
            acc[i] = (hi ? acc[i + half] : acc[i]) + got;
        }
    }
    float sum = acc[0];
#pragma unroll
    for (int offx = M; offx < 64; offx <<= 1) sum += __shfl_xor(sum, offx);

    __shared__ float red[4][M];
    int o = (int)(__brev((unsigned)(lane & (M - 1))) >> (32 - LOG2M));
    if (lane < M) red[wv][o] = sum;
    __syncthreads();

    if (tid < M) {
        float tot = red[0][tid] + red[1][tid] + red[2][tid] + red[3][tid];
        int b = tid / SS, p = tid % SS;
        size_t idx = (size_t)(b * OC + oc) * SS + p;
        float mo;
        float val = lif_update(mem[idx], tot, thr_v[layer], leak_v[layer], &mo);
        mem[idx] = mo;
        out[idx] = val;
    }
}

__global__ void avgpool_kernel(const float* __restrict__ in,
                               float* __restrict__ out,
                               int C, int Ho, int Wo, int n) {
    int idx = blockIdx.x * blockDim.x + threadIdx.x;
    if (idx >= n) return;
    int x = idx % Wo;
    int y = (idx / Wo) % Ho;
    int c = (idx / (Wo * Ho)) % C;
    int b = idx / (Wo * Ho * C);
    int Wi = Wo * 2, Hi = Ho * 2;
    const float* ip = in + ((size_t)b * C + c) * Hi * Wi;
    float s = ip[(2 * y) * Wi + 2 * x] + ip[(2 * y) * Wi + 2 * x + 1] +
              ip[(2 * y + 1) * Wi + 2 * x] + ip[(2 * y + 1) * Wi + 2 * x + 1];
    out[idx] = s * 0.25f;
}

// Wave-per-output-neuron FC+LIF (float4 K-split, 4-batch reuse).
__global__ void fc_lif_wave_kernel(const float* __restrict__ in,
                                   const float* __restrict__ w,
                                   float* __restrict__ mem,
                                   float* __restrict__ out,
                                   const float* __restrict__ thr_v,
                                   const float* __restrict__ leak_v,
                                   int layer, int Kd, int N) {
    int wave = (blockIdx.x * blockDim.x + threadIdx.x) >> 6;
    int lane = threadIdx.x & 63;
    if (wave >= N) return;
    int j = wave;
    int K4 = Kd >> 2;
    const float4* wp = (const float4*)(w + (size_t)j * Kd);
    const float4* ip = (const float4*)in;
    float a0 = 0.f, a1 = 0.f, a2 = 0.f, a3 = 0.f;
    for (int k = lane; k < K4; k += 64) {
        float4 wv = wp[k];
        float4 v0 = ip[k];
        float4 v1 = ip[K4 + k];
        float4 v2 = ip[2 * K4 + k];
        float4 v3 = ip[3 * K4 + k];
        a0 = fmaf(wv.x, v0.x, fmaf(wv.y, v0.y, fmaf(wv.z, v0.z, fmaf(wv.w, v0.w, a0))));
        a1 = fmaf(wv.x, v1.x, fmaf(wv.y, v1.y, fmaf(wv.z, v1.z, fmaf(wv.w, v1.w, a1))));
        a2 = fmaf(wv.x, v2.x, fmaf(wv.y, v2.y, fmaf(wv.z, v2.z, fmaf(wv.w, v2.w, a2))));
        a3 = fmaf(wv.x, v3.x, fmaf(wv.y, v3.y, fmaf(wv.z, v3.z, fmaf(wv.w, v3.w, a3))));
    }
#pragma unroll
    for (int off = 32; off > 0; off >>= 1) {
        a0 += __shfl_xor(a0, off);
        a1 += __shfl_xor(a1, off);
        a2 += __shfl_xor(a2, off);
        a3 += __shfl_xor(a3, off);
    }
    if (lane == 0) {
        float thr = thr_v[layer], leak = leak_v[layer];
        float accv[4] = {a0, a1, a2, a3};
#pragma unroll
        for (int b = 0; b < BATCH; ++b) {
            float mo;
            float val = lif_update(mem[(size_t)b * N + j], accv[b], thr, leak, &mo);
            mem[(size_t)b * N + j] = mo;
            out[(size_t)b * N + j] = val;
        }
    }
}

// One 64-thread block per (b, label). logits += in[b,:] . w[l,:]
__global__ void fc2_acc_kernel(const float* __restrict__ in,
                               const float* __restrict__ w,
                               float* __restrict__ logits,
                               int Kd, int L) {
    int o = blockIdx.x;
    int l = o % L;
    int b = o / L;
    int K4 = Kd >> 2;
    const float4* ip = (const float4*)(in + (size_t)b * Kd);
    const float4* wp = (const float4*)(w + (size_t)l * Kd);
    float s = 0.f;
    for (int k = threadIdx.x; k < K4; k += 64) {
        float4 iv = ip[k];
        float4 wv = wp[k];
        s = fmaf(iv.x, wv.x, fmaf(iv.y, wv.y, fmaf(iv.z, wv.z, fmaf(iv.w, wv.w, s))));
    }
#pragma unroll
    for (int off = 32; off > 0; off >>= 1) s += __shfl_xor(s, off);
    if (threadIdx.x == 0) logits[o] += s;
}

extern "C" void kernel_launch(void* const* d_in, const int* in_sizes, int n_in,
                              void* d_out, int out_size, void* d_ws, size_t ws_size,
                              hipStream_t stream) {
    const float* x = (const float*)d_in[0];
    const float* convw[13];
    for (int i = 0; i < 13; ++i) convw[i] = (const float*)d_in[1 + i];
    const float* fc0 = (const float*)d_in[14];
    const float* fc1 = (const float*)d_in[15];
    const float* fc2 = (const float*)d_in[16];
    const float* thr = (const float*)d_in[17];
    const float* leak = (const float*)d_in[18];

    static const int IC[13] = {3, 64, 64, 128, 128, 256, 256, 256, 512, 512, 512, 512, 512};
    static const int OC[13] = {64, 64, 128, 128, 256, 256, 256, 512, 512, 512, 512, 512, 512};
    static const int HH[13] = {32, 32, 16, 16, 8, 8, 8, 4, 4, 4, 2, 2, 2};
    static const bool PA[13] = {false, true, false, true, false, false, true,
                                false, false, true, false, false, false};

    float* ws = (float*)d_ws;
    size_t off = 0;
    float* convmem[13];
    for (int i = 0; i < 13; ++i) {
        convmem[i] = ws + off;
        off += (size_t)BATCH * OC[i] * HH[i] * HH[i];
    }
    float* mfc0 = ws + off; off += BATCH * 4096;
    float* mfc1 = ws + off; off += BATCH * 4096;
    size_t mem_floats = off;
    float* bufs[3];
    for (int i = 0; i < 3; ++i) { bufs[i] = ws + off; off += 262144; }

    hipMemsetAsync(d_ws, 0, mem_floats * sizeof(float), stream);
    hipMemsetAsync(d_out, 0, (size_t)out_size * sizeof(float), stream);

    for (int t = 0; t < 3; ++t) {
        const float* src = x;
        int cur = -1;
        for (int i = 0; i < 13; ++i) {
            int d = (cur + 1) % 3;
            if (cur < 0) d = 0;
            int H = HH[i], W = HH[i];
            if (i == 0) {
                int n = BATCH * OC[i] * H * W;
                conv_lif_kernel<<<(n + 255) / 256, 256, 0, stream>>>(
                    src, convw[i], convmem[i], bufs[d], thr, leak, i,
                    IC[i], OC[i], H, W, n);
            } else if (H >= 8) {
                if (i == 1) {
                    // IC=64: 4 waves, OCT=8
                    int blocks = BATCH * (H * W / 64) * (OC[i] / 8);
                    conv_mid_kernel<8, 4><<<blocks, 256, 0, stream>>>(
                        src, convw[i], convmem[i], bufs[d], thr, leak, i,
                        IC[i], OC[i], H, W);
                } else if (i == 2) {
                    // IC=64: 4 waves, OCT=4
                    int blocks = BATCH * (H * W / 64) * (OC[i] / 4);
                    conv_mid_kernel<4, 4><<<blocks, 256, 0, stream>>>(
                        src, convw[i], convmem[i], bufs[d], thr, leak, i,
                        IC[i], OC[i], H, W);
                } else {
                    // IC>=128: 8 waves, OCT=4
                    int blocks = BATCH * (H * W / 64) * (OC[i] / 4);
                    conv_mid_kernel<4, 8><<<blocks, 512, 0, stream>>>(
                        src, convw[i], convmem[i], bufs[d], thr, leak, i,
                        IC[i], OC[i], H, W);
                }
            } else if (H == 4) {
                conv_small4_kernel<4><<<OC[i], 256, 0, stream>>>(
                    src, convw[i], convmem[i], bufs[d], thr, leak, i, IC[i], OC[i]);
            } else {  // H == 2
                conv_small4_kernel<2><<<OC[i], 256, 0, stream>>>(
                    src, convw[i], convmem[i], bufs[d], thr, leak, i, IC[i], OC[i]);
            }
            cur = d; src = bufs[cur];
            if (PA[i]) {
                int p = (cur + 1) % 3;
                int Ho = HH[i] / 2;
                int np = BATCH * OC[i] * Ho * Ho;
                avgpool_kernel<<<(np + 255) / 256, 256, 0, stream>>>(
                    src, bufs[p], OC[i], Ho, Ho, np);
                cur = p; src = bufs[p];
            }
        }
        {
            int d = (cur + 1) % 3;
            fc_lif_wave_kernel<<<(4096 * 64) / 256, 256, 0, stream>>>(
                src, fc0, mfc0, bufs[d], thr, leak, 13, 2048, 4096);
            cur = d; src = bufs[cur];
        }
        {
            int d = (cur + 1) % 3;
            fc_lif_wave_kernel<<<(4096 * 64) / 256, 256, 0, stream>>>(
                src, fc1, mfc1, bufs[d], thr, leak, 14, 4096, 4096);
            cur = d; src = bufs[cur];
        }
        fc2_acc_kernel<<<BATCH * 10, 64, 0, stream>>>(src, fc2, (float*)d_out, 4096, 10);
    }
}

// Round 5
// 957.037 us; speedup vs baseline: 3.9818x; 3.9818x over previous
//
#include <hip/hip_runtime.h>

// VGG16-A spiking NN, multi-compartment LIF (K=2), T=3, B=4, fp32.
// Round 5: round-4 structure (NW-wave IC split + LDS reduce) with the
// spill-inducing `#pragma unroll 4` REMOVED (round 4: SGPR/VGPR blowup ->
// scratch spill -> 283 MB WRITE_SIZE per dispatch). Inner loop body is the
// proven 24-VGPR round-3 version.

#define BATCH 4

__device__ __forceinline__ float lif_update(float mem_in, float syn, float thr,
                                            float leak, float* mem_out) {
    float m = leak * mem_in + syn;
    float val = 0.f;
    if ((m / thr - 1.f > 0.f) && (1.f - m / (2.f * thr) >= 0.f)) val += 1.f;
    if ((m / (2.f * thr) - 1.f > 0.f) && (1.f - m / (4.f * thr) >= 0.f)) val += 2.f;
    *mem_out = m - thr * val;
    return val;
}

// Element-per-thread conv+LIF (layer 0 only, IC=3).
__global__ void conv_lif_kernel(const float* __restrict__ in,
                                const float* __restrict__ w,
                                float* __restrict__ mem,
                                float* __restrict__ out,
                                const float* __restrict__ thr_v,
                                const float* __restrict__ leak_v,
                                int layer, int IC, int OC, int H, int W, int n) {
    int idx = blockIdx.x * blockDim.x + threadIdx.x;
    if (idx >= n) return;
    int x  = idx % W;
    int y  = (idx / W) % H;
    int oc = (idx / (W * H)) % OC;
    int b  = idx / (W * H * OC);

    const float* wp = w + (size_t)oc * IC * 9;
    const float* ip = in + (size_t)b * IC * H * W;

    float syn = 0.f;
    for (int ic = 0; ic < IC; ++ic) {
        const float* ipc = ip + (size_t)ic * H * W;
        const float* wpc = wp + ic * 9;
#pragma unroll
        for (int ky = 0; ky < 3; ++ky) {
            int yy = y + ky - 1;
            if (yy < 0 || yy >= H) continue;
#pragma unroll
            for (int kx = 0; kx < 3; ++kx) {
                int xx = x + kx - 1;
                if (xx < 0 || xx >= W) continue;
                syn = fmaf(ipc[yy * W + xx], wpc[ky * 3 + kx], syn);
            }
        }
    }
    float mo;
    float val = lif_update(mem[idx], syn, thr_v[layer], leak_v[layer], &mo);
    mem[idx] = mo;
    out[idx] = val;
}

// Layers 1-6. Block = NW waves. blockIdx -> (b, pixel-chunk, oc-group).
// Lane = pixel within 64-pixel chunk. Wave wv accumulates over its IC/NW
// channel chunk into acc[OCT]; LDS reduce across waves; 1 thread/output LIF.
template <int OCT, int NW>
__global__ void conv_mid_kernel(const float* __restrict__ in,
                                const float* __restrict__ w,
                                float* __restrict__ mem,
                                float* __restrict__ out,
                                const float* __restrict__ thr_v,
                                const float* __restrict__ leak_v,
                                int layer, int IC, int OC, int H, int W) {
    int tid = threadIdx.x;
    int lane = tid & 63;
    int wv = tid >> 6;  // 0..NW-1
    int ocg = OC / OCT;
    int HW = H * W;
    int chunks = HW >> 6;
    int bid = blockIdx.x;
    int g  = bid % ocg;
    int ch = (bid / ocg) % chunks;
    int b  = bid / (ocg * chunks);
    int rpw = 64 / W;
    int y = ch * rpw + lane / W;
    int x = lane % W;
    int oc0 = g * OCT;

    int off[9];
    bool msk[9];
#pragma unroll
    for (int ky = 0; ky < 3; ++ky)
#pragma unroll
        for (int kx = 0; kx < 3; ++kx) {
            int yy = y + ky - 1, xx = x + kx - 1;
            bool v = (yy >= 0 && yy < H && xx >= 0 && xx < W);
            msk[ky * 3 + kx] = v;
            off[ky * 3 + kx] = v ? yy * W + xx : 0;
        }

    float acc[OCT];
#pragma unroll
    for (int t = 0; t < OCT; ++t) acc[t] = 0.f;

    const float* ibase = in + (size_t)b * IC * HW;
    const float* wbase = w + (size_t)oc0 * IC * 9;

    int icpw = IC / NW;
    int ic0 = wv * icpw;
    for (int ic = ic0; ic < ic0 + icpw; ++ic) {
        const float* ip = ibase + (size_t)ic * HW;
        float v[9];
#pragma unroll
        for (int k = 0; k < 9; ++k) v[k] = msk[k] ? ip[off[k]] : 0.f;
        const float* wp = wbase + (size_t)ic * 9;
#pragma unroll
        for (int t = 0; t < OCT; ++t) {
            const float* wt = wp + (size_t)t * IC * 9;
#pragma unroll
            for (int k = 0; k < 9; ++k) acc[t] = fmaf(v[k], wt[k], acc[t]);
        }
    }

    __shared__ float red[NW][OCT][64];
#pragma unroll
    for (int t = 0; t < OCT; ++t) red[wv][t][lane] = acc[t];
    __syncthreads();

    float thr = thr_v[layer], leak = leak_v[layer];
    for (int s = tid; s < OCT * 64; s += NW * 64) {
        int t = s >> 6, p = s & 63;
        float sum = 0.f;
#pragma unroll
        for (int q = 0; q < NW; ++q) sum += red[q][t][p];
        size_t idx = (size_t)(b * OC + oc0 + t) * HW + ch * 64 + p;
        float mo;
        float val = lif_update(mem[idx], sum, thr, leak, &mo);
        mem[idx] = mo;
        out[idx] = val;
    }
}

// Layers 7-12 (4x4 / 2x2 planes). Block = 4 waves, one oc per block.
// ic = lane + 64*wv (+256*pass). Whole S x S plane for all 4 batches in
// registers; per-wave butterfly transpose-reduce; LDS [4][M] cross-wave
// reduce; parallel LIF epilogue.
template <int S>
__global__ void conv_small4_kernel(const float* __restrict__ in,
                                   const float* __restrict__ w,
                                   float* __restrict__ mem,
                                   float* __restrict__ out,
                                   const float* __restrict__ thr_v,
                                   const float* __restrict__ leak_v,
                                   int layer, int IC, int OC) {
    constexpr int SS = S * S;
    constexpr int M = 4 * SS;              // 64 (S=4) or 16 (S=2)
    constexpr int LOG2M = (S == 4) ? 6 : 4;
    int tid = threadIdx.x;
    int lane = tid & 63;
    int wv = tid >> 6;  // 0..3
    int oc = blockIdx.x;

    float acc[M];
#pragma unroll
    for (int i = 0; i < M; ++i) acc[i] = 0.f;

    const float* wrow = w + (size_t)oc * IC * 9;
    for (int ic = lane + (wv << 6); ic < IC; ic += 256) {
        const float* wp = wrow + (size_t)ic * 9;
        float wvv[9];
#pragma unroll
        for (int k = 0; k < 9; ++k) wvv[k] = wp[k];
#pragma unroll
        for (int b = 0; b < 4; ++b) {
            const float4* ip = (const float4*)(in + (size_t)(b * IC + ic) * SS);
            float pv[SS];
#pragma unroll
            for (int q = 0; q < SS / 4; ++q) {
                float4 t4 = ip[q];
                pv[4 * q + 0] = t4.x;
                pv[4 * q + 1] = t4.y;
                pv[4 * q + 2] = t4.z;
                pv[4 * q + 3] = t4.w;
            }
#pragma unroll
            for (int y = 0; y < S; ++y)
#pragma unroll
                for (int x = 0; x < S; ++x) {
                    float a = acc[b * SS + y * S + x];
#pragma unroll
                    for (int ky = 0; ky < 3; ++ky) {
                        int yy = y + ky - 1;
                        if (yy < 0 || yy >= S) continue;
#pragma unroll
                        for (int kx = 0; kx < 3; ++kx) {
                            int xx = x + kx - 1;
                            if (xx < 0 || xx >= S) continue;
                            a = fmaf(pv[yy * S + xx], wvv[ky * 3 + kx], a);
                        }
                    }
                    acc[b * SS + y * S + x] = a;
                }
        }
    }

    // per-wave transpose-reduce: M accs across 64 lanes -> 1 value per lane
#pragma unroll
    for (int step = 0; step < LOG2M; ++step) {
        const int offx = 1 << step;
        const int half = M >> (step + 1);
        const bool hi = (lane & offx) != 0;
#pragma unroll
        for (int i = 0; i < half; ++i) {
            float sent = hi ? acc[i] : acc[i + half];
            float got = __shfl_xor(sent, offx);
            acc[i] = (hi ? acc[i + half] : acc[i]) + got;
        }
    }
    float sum = acc[0];
#pragma unroll
    for (int offx = M; offx < 64; offx <<= 1) sum += __shfl_xor(sum, offx);

    __shared__ float red[4][M];
    int o = (int)(__brev((unsigned)(lane & (M - 1))) >> (32 - LOG2M));
    if (lane < M) red[wv][o] = sum;
    __syncthreads();

    if (tid < M) {
        float tot = red[0][tid] + red[1][tid] + red[2][tid] + red[3][tid];
        int b = tid / SS, p = tid % SS;
        size_t idx = (size_t)(b * OC + oc) * SS + p;
        float mo;
        float val = lif_update(mem[idx], tot, thr_v[layer], leak_v[layer], &mo);
        mem[idx] = mo;
        out[idx] = val;
    }
}

__global__ void avgpool_kernel(const float* __restrict__ in,
                               float* __restrict__ out,
                               int C, int Ho, int Wo, int n) {
    int idx = blockIdx.x * blockDim.x + threadIdx.x;
    if (idx >= n) return;
    int x = idx % Wo;
    int y = (idx / Wo) % Ho;
    int c = (idx / (Wo * Ho)) % C;
    int b = idx / (Wo * Ho * C);
    int Wi = Wo * 2, Hi = Ho * 2;
    const float* ip = in + ((size_t)b * C + c) * Hi * Wi;
    float s = ip[(2 * y) * Wi + 2 * x] + ip[(2 * y) * Wi + 2 * x + 1] +
              ip[(2 * y + 1) * Wi + 2 * x] + ip[(2 * y + 1) * Wi + 2 * x + 1];
    out[idx] = s * 0.25f;
}

// Wave-per-output-neuron FC+LIF (float4 K-split, 4-batch reuse).
__global__ void fc_lif_wave_kernel(const float* __restrict__ in,
                                   const float* __restrict__ w,
                                   float* __restrict__ mem,
                                   float* __restrict__ out,
                                   const float* __restrict__ thr_v,
                                   const float* __restrict__ leak_v,
                                   int layer, int Kd, int N) {
    int wave = (blockIdx.x * blockDim.x + threadIdx.x) >> 6;
    int lane = threadIdx.x & 63;
    if (wave >= N) return;
    int j = wave;
    int K4 = Kd >> 2;
    const float4* wp = (const float4*)(w + (size_t)j * Kd);
    const float4* ip = (const float4*)in;
    float a0 = 0.f, a1 = 0.f, a2 = 0.f, a3 = 0.f;
    for (int k = lane; k < K4; k += 64) {
        float4 wv = wp[k];
        float4 v0 = ip[k];
        float4 v1 = ip[K4 + k];
        float4 v2 = ip[2 * K4 + k];
        float4 v3 = ip[3 * K4 + k];
        a0 = fmaf(wv.x, v0.x, fmaf(wv.y, v0.y, fmaf(wv.z, v0.z, fmaf(wv.w, v0.w, a0))));
        a1 = fmaf(wv.x, v1.x, fmaf(wv.y, v1.y, fmaf(wv.z, v1.z, fmaf(wv.w, v1.w, a1))));
        a2 = fmaf(wv.x, v2.x, fmaf(wv.y, v2.y, fmaf(wv.z, v2.z, fmaf(wv.w, v2.w, a2))));
        a3 = fmaf(wv.x, v3.x, fmaf(wv.y, v3.y, fmaf(wv.z, v3.z, fmaf(wv.w, v3.w, a3))));
    }
#pragma unroll
    for (int off = 32; off > 0; off >>= 1) {
        a0 += __shfl_xor(a0, off);
        a1 += __shfl_xor(a1, off);
        a2 += __shfl_xor(a2, off);
        a3 += __shfl_xor(a3, off);
    }
    if (lane == 0) {
        float thr = thr_v[layer], leak = leak_v[layer];
        float accv[4] = {a0, a1, a2, a3};
#pragma unroll
        for (int b = 0; b < BATCH; ++b) {
            float mo;
            float val = lif_update(mem[(size_t)b * N + j], accv[b], thr, leak, &mo);
            mem[(size_t)b * N + j] = mo;
            out[(size_t)b * N + j] = val;
        }
    }
}

// One 64-thread block per (b, label). logits += in[b,:] . w[l,:]
__global__ void fc2_acc_kernel(const float* __restrict__ in,
                               const float* __restrict__ w,
                               float* __restrict__ logits,
                               int Kd, int L) {
    int o = blockIdx.x;
    int l = o % L;
    int b = o / L;
    int K4 = Kd >> 2;
    const float4* ip = (const float4*)(in + (size_t)b * Kd);
    const float4* wp = (const float4*)(w + (size_t)l * Kd);
    float s = 0.f;
    for (int k = threadIdx.x; k < K4; k += 64) {
        float4 iv = ip[k];
        float4 wv = wp[k];
        s = fmaf(iv.x, wv.x, fmaf(iv.y, wv.y, fmaf(iv.z, wv.z, fmaf(iv.w, wv.w, s))));
    }
#pragma unroll
    for (int off = 32; off > 0; off >>= 1) s += __shfl_xor(s, off);
    if (threadIdx.x == 0) logits[o] += s;
}

extern "C" void kernel_launch(void* const* d_in, const int* in_sizes, int n_in,
                              void* d_out, int out_size, void* d_ws, size_t ws_size,
                              hipStream_t stream) {
    const float* x = (const float*)d_in[0];
    const float* convw[13];
    for (int i = 0; i < 13; ++i) convw[i] = (const float*)d_in[1 + i];
    const float* fc0 = (const float*)d_in[14];
    const float* fc1 = (const float*)d_in[15];
    const float* fc2 = (const float*)d_in[16];
    const float* thr = (const float*)d_in[17];
    const float* leak = (const float*)d_in[18];

    static const int IC[13] = {3, 64, 64, 128, 128, 256, 256, 256, 512, 512, 512, 512, 512};
    static const int OC[13] = {64, 64, 128, 128, 256, 256, 256, 512, 512, 512, 512, 512, 512};
    static const int HH[13] = {32, 32, 16, 16, 8, 8, 8, 4, 4, 4, 2, 2, 2};
    static const bool PA[13] = {false, true, false, true, false, false, true,
                                false, false, true, false, false, false};

    float* ws = (float*)d_ws;
    size_t off = 0;
    float* convmem[13];
    for (int i = 0; i < 13; ++i) {
        convmem[i] = ws + off;
        off += (size_t)BATCH * OC[i] * HH[i] * HH[i];
    }
    float* mfc0 = ws + off; off += BATCH * 4096;
    float* mfc1 = ws + off; off += BATCH * 4096;
    size_t mem_floats = off;
    float* bufs[3];
    for (int i = 0; i < 3; ++i) { bufs[i] = ws + off; off += 262144; }

    hipMemsetAsync(d_ws, 0, mem_floats * sizeof(float), stream);
    hipMemsetAsync(d_out, 0, (size_t)out_size * sizeof(float), stream);

    for (int t = 0; t < 3; ++t) {
        const float* src = x;
        int cur = -1;
        for (int i = 0; i < 13; ++i) {
            int d = (cur + 1) % 3;
            if (cur < 0) d = 0;
            int H = HH[i], W = HH[i];
            if (i == 0) {
                int n = BATCH * OC[i] * H * W;
                conv_lif_kernel<<<(n + 255) / 256, 256, 0, stream>>>(
                    src, convw[i], convmem[i], bufs[d], thr, leak, i,
                    IC[i], OC[i], H, W, n);
            } else if (H >= 8) {
                if (i == 1) {
                    // IC=64: 4 waves, OCT=8
                    int blocks = BATCH * (H * W / 64) * (OC[i] / 8);
                    conv_mid_kernel<8, 4><<<blocks, 256, 0, stream>>>(
                        src, convw[i], convmem[i], bufs[d], thr, leak, i,
                        IC[i], OC[i], H, W);
                } else if (i == 2) {
                    // IC=64: 4 waves, OCT=4
                    int blocks = BATCH * (H * W / 64) * (OC[i] / 4);
                    conv_mid_kernel<4, 4><<<blocks, 256, 0, stream>>>(
                        src, convw[i], convmem[i], bufs[d], thr, leak, i,
                        IC[i], OC[i], H, W);
                } else {
                    // IC>=128: 8 waves, OCT=4
                    int blocks = BATCH * (H * W / 64) * (OC[i] / 4);
                    conv_mid_kernel<4, 8><<<blocks, 512, 0, stream>>>(
                        src, convw[i], convmem[i], bufs[d], thr, leak, i,
                        IC[i], OC[i], H, W);
                }
            } else if (H == 4) {
                conv_small4_kernel<4><<<OC[i], 256, 0, stream>>>(
                    src, convw[i], convmem[i], bufs[d], thr, leak, i, IC[i], OC[i]);
            } else {  // H == 2
                conv_small4_kernel<2><<<OC[i], 256, 0, stream>>>(
                    src, convw[i], convmem[i], bufs[d], thr, leak, i, IC[i], OC[i]);
            }
            cur = d; src = bufs[cur];
            if (PA[i]) {
                int p = (cur + 1) % 3;
                int Ho = HH[i] / 2;
                int np = BATCH * OC[i] * Ho * Ho;
                avgpool_kernel<<<(np + 255) / 256, 256, 0, stream>>>(
                    src, bufs[p], OC[i], Ho, Ho, np);
                cur = p; src = bufs[p];
            }
        }
        {
            int d = (cur + 1) % 3;
            fc_lif_wave_kernel<<<(4096 * 64) / 256, 256, 0, stream>>>(
                src, fc0, mfc0, bufs[d], thr, leak, 13, 2048, 4096);
            cur = d; src = bufs[cur];
        }
        {
            int d = (cur + 1) % 3;
            fc_lif_wave_kernel<<<(4096 * 64) / 256, 256, 0, stream>>>(
                src, fc1, mfc1, bufs[d], thr, leak, 14, 4096, 4096);
            cur = d; src = bufs[cur];
        }
        fc2_acc_kernel<<<BATCH * 10, 64, 0, stream>>>(src, fc2, (float*)d_out, 4096, 10);
    }
}

// Round 6
// 914.182 us; speedup vs baseline: 4.1685x; 1.0469x over previous
//
#include <hip/hip_runtime.h>

// VGG16-A spiking NN, multi-compartment LIF (K=2), T=3, B=4, fp32.
// Round 6:
//  - conv_mid inner loop software-pipelined (prefetch next ic's 9 inputs
//    before current FMAs) — hides the ~200cyc load latency per iteration.
//  - avgpool fused into conv epilogues (spikes pooled in LDS, pooled buffer
//    written directly): removes 12 dispatches.
//  - `first` flag (t==0): membranes treated as 0, fc2 overwrites logits —
//    removes both memsets.

#define BATCH 4

__device__ __forceinline__ float lif_update(float mem_in, float syn, float thr,
                                            float leak, float* mem_out) {
    float m = leak * mem_in + syn;
    float val = 0.f;
    if ((m / thr - 1.f > 0.f) && (1.f - m / (2.f * thr) >= 0.f)) val += 1.f;
    if ((m / (2.f * thr) - 1.f > 0.f) && (1.f - m / (4.f * thr) >= 0.f)) val += 2.f;
    *mem_out = m - thr * val;
    return val;
}

// Element-per-thread conv+LIF (layer 0 only, IC=3).
__global__ void conv_lif_kernel(const float* __restrict__ in,
                                const float* __restrict__ w,
                                float* __restrict__ mem,
                                float* __restrict__ out,
                                const float* __restrict__ thr_v,
                                const float* __restrict__ leak_v,
                                int layer, int IC, int OC, int H, int W, int n,
                                int first) {
    int idx = blockIdx.x * blockDim.x + threadIdx.x;
    if (idx >= n) return;
    int x  = idx % W;
    int y  = (idx / W) % H;
    int oc = (idx / (W * H)) % OC;
    int b  = idx / (W * H * OC);

    const float* wp = w + (size_t)oc * IC * 9;
    const float* ip = in + (size_t)b * IC * H * W;

    float syn = 0.f;
    for (int ic = 0; ic < IC; ++ic) {
        const float* ipc = ip + (size_t)ic * H * W;
        const float* wpc = wp + ic * 9;
#pragma unroll
        for (int ky = 0; ky < 3; ++ky) {
            int yy = y + ky - 1;
            if (yy < 0 || yy >= H) continue;
#pragma unroll
            for (int kx = 0; kx < 3; ++kx) {
                int xx = x + kx - 1;
                if (xx < 0 || xx >= W) continue;
                syn = fmaf(ipc[yy * W + xx], wpc[ky * 3 + kx], syn);
            }
        }
    }
    float mi = first ? 0.f : mem[idx];
    float mo;
    float val = lif_update(mi, syn, thr_v[layer], leak_v[layer], &mo);
    mem[idx] = mo;
    out[idx] = val;
}

// Layers 1-6. Block = NW waves. blockIdx -> (b, pixel-chunk, oc-group).
// Lane = pixel within 64-pixel chunk. Wave wv accumulates over its IC/NW
// channel chunk into acc[OCT] (inner loop software-pipelined); LDS reduce
// across waves; LIF; optional fused 2x2 avg-pool writing pooled out.
template <int OCT, int NW, int POOL>
__global__ void conv_mid_kernel(const float* __restrict__ in,
                                const float* __restrict__ w,
                                float* __restrict__ mem,
                                float* __restrict__ out,
                                const float* __restrict__ thr_v,
                                const float* __restrict__ leak_v,
                                int layer, int IC, int OC, int H, int W,
                                int first) {
    int tid = threadIdx.x;
    int lane = tid & 63;
    int wv = tid >> 6;  // 0..NW-1
    int ocg = OC / OCT;
    int HW = H * W;
    int chunks = HW >> 6;
    int bid = blockIdx.x;
    int g  = bid % ocg;
    int ch = (bid / ocg) % chunks;
    int b  = bid / (ocg * chunks);
    int rpw = 64 / W;
    int y = ch * rpw + lane / W;
    int x = lane % W;
    int oc0 = g * OCT;

    int off[9];
    bool msk[9];
#pragma unroll
    for (int ky = 0; ky < 3; ++ky)
#pragma unroll
        for (int kx = 0; kx < 3; ++kx) {
            int yy = y + ky - 1, xx = x + kx - 1;
            bool v = (yy >= 0 && yy < H && xx >= 0 && xx < W);
            msk[ky * 3 + kx] = v;
            off[ky * 3 + kx] = v ? yy * W + xx : 0;
        }

    float acc[OCT];
#pragma unroll
    for (int t = 0; t < OCT; ++t) acc[t] = 0.f;

    const float* ibase = in + (size_t)b * IC * HW;
    const float* wbase = w + (size_t)oc0 * IC * 9;

    int icpw = IC / NW;
    int ic0 = wv * icpw;
    int icend = ic0 + icpw;

    // software pipeline: v holds current ic's inputs, prefetch next into nv
    float v[9];
    {
        const float* ip = ibase + (size_t)ic0 * HW;
#pragma unroll
        for (int k = 0; k < 9; ++k) v[k] = msk[k] ? ip[off[k]] : 0.f;
    }
    for (int ic = ic0; ic < icend; ++ic) {
        int icn = (ic + 1 < icend) ? ic + 1 : ic;
        const float* ipn = ibase + (size_t)icn * HW;
        float nv[9];
#pragma unroll
        for (int k = 0; k < 9; ++k) nv[k] = msk[k] ? ipn[off[k]] : 0.f;

        const float* wp = wbase + (size_t)ic * 9;
#pragma unroll
        for (int t = 0; t < OCT; ++t) {
            const float* wt = wp + (size_t)t * IC * 9;
#pragma unroll
            for (int k = 0; k < 9; ++k) acc[t] = fmaf(v[k], wt[k], acc[t]);
        }
#pragma unroll
        for (int k = 0; k < 9; ++k) v[k] = nv[k];
    }

    __shared__ float red[NW][OCT][64];
#pragma unroll
    for (int t = 0; t < OCT; ++t) red[wv][t][lane] = acc[t];
    __syncthreads();

    __shared__ float vals[OCT][64];
    float thr = thr_v[layer], leak = leak_v[layer];
    for (int s = tid; s < OCT * 64; s += NW * 64) {
        int t = s >> 6, p = s & 63;
        float sum = 0.f;
#pragma unroll
        for (int q = 0; q < NW; ++q) sum += red[q][t][p];
        size_t idx = (size_t)(b * OC + oc0 + t) * HW + ch * 64 + p;
        float mi = first ? 0.f : mem[idx];
        float mo;
        float val = lif_update(mi, sum, thr, leak, &mo);
        mem[idx] = mo;
        if (POOL) vals[t][p] = val;
        else out[idx] = val;
    }
    if (POOL) {
        __syncthreads();
        int Wo = W >> 1, Ho = H >> 1;
        for (int s = tid; s < OCT * 16; s += NW * 64) {
            int t = s >> 4, q = s & 15;
            int pr = q / Wo, pc = q % Wo;
            float pv = 0.25f * (vals[t][(2 * pr) * W + 2 * pc] +
                                vals[t][(2 * pr) * W + 2 * pc + 1] +
                                vals[t][(2 * pr + 1) * W + 2 * pc] +
                                vals[t][(2 * pr + 1) * W + 2 * pc + 1]);
            size_t pidx = ((size_t)(b * OC + oc0 + t) * Ho +
                           (ch * (rpw >> 1) + pr)) * Wo + pc;
            out[pidx] = pv;
        }
    }
}

// Layers 7-12 (4x4 / 2x2 planes). Block = 4 waves, one oc per block.
// ic = lane + 64*wv (+256*pass). Per-wave butterfly transpose-reduce;
// LDS [4][M] cross-wave reduce; parallel LIF; optional fused pool.
template <int S, int POOL>
__global__ void conv_small4_kernel(const float* __restrict__ in,
                                   const float* __restrict__ w,
                                   float* __restrict__ mem,
                                   float* __restrict__ out,
                                   const float* __restrict__ thr_v,
                                   const float* __restrict__ leak_v,
                                   int layer, int IC, int OC, int first) {
    constexpr int SS = S * S;
    constexpr int M = 4 * SS;              // 64 (S=4) or 16 (S=2)
    constexpr int LOG2M = (S == 4) ? 6 : 4;
    int tid = threadIdx.x;
    int lane = tid & 63;
    int wv = tid >> 6;  // 0..3
    int oc = blockIdx.x;

    float acc[M];
#pragma unroll
    for (int i = 0; i < M; ++i) acc[i] = 0.f;

    const float* wrow = w + (size_t)oc * IC * 9;
    for (int ic = lane + (wv << 6); ic < IC; ic += 256) {
        const float* wp = wrow + (size_t)ic * 9;
        float wvv[9];
#pragma unroll
        for (int k = 0; k < 9; ++k) wvv[k] = wp[k];
#pragma unroll
        for (int b = 0; b < 4; ++b) {
            const float4* ip = (const float4*)(in + (size_t)(b * IC + ic) * SS);
            float pv[SS];
#pragma unroll
            for (int q = 0; q < SS / 4; ++q) {
                float4 t4 = ip[q];
                pv[4 * q + 0] = t4.x;
                pv[4 * q + 1] = t4.y;
                pv[4 * q + 2] = t4.z;
                pv[4 * q + 3] = t4.w;
            }
#pragma unroll
            for (int y = 0; y < S; ++y)
#pragma unroll
                for (int x = 0; x < S; ++x) {
                    float a = acc[b * SS + y * S + x];
#pragma unroll
                    for (int ky = 0; ky < 3; ++ky) {
                        int yy = y + ky - 1;
                        if (yy < 0 || yy >= S) continue;
#pragma unroll
                        for (int kx = 0; kx < 3; ++kx) {
                            int xx = x + kx - 1;
                            if (xx < 0 || xx >= S) continue;
                            a = fmaf(pv[yy * S + xx], wvv[ky * 3 + kx], a);
                        }
                    }
                    acc[b * SS + y * S + x] = a;
                }
        }
    }

    // per-wave transpose-reduce: M accs across 64 lanes -> 1 value per lane
#pragma unroll
    for (int step = 0; step < LOG2M; ++step) {
        const int offx = 1 << step;
        const int half = M >> (step + 1);
        const bool hi = (lane & offx) != 0;
#pragma unroll
        for (int i = 0; i < half; ++i) {
            float sent = hi ? acc[i] : acc[i + half];
            float got = __shfl_xor(sent, offx);
            acc[i] = (hi ? acc[i + half] : acc[i]) + got;
        }
    }
    float sum = acc[0];
#pragma unroll
    for (int offx = M; offx < 64; offx <<= 1) sum += __shfl_xor(sum, offx);

    __shared__ float red[4][M];
    int o = (int)(__brev((unsigned)(lane & (M - 1))) >> (32 - LOG2M));
    if (lane < M) red[wv][o] = sum;
    __syncthreads();

    __shared__ float pvs[M];
    if (tid < M) {
        float tot = red[0][tid] + red[1][tid] + red[2][tid] + red[3][tid];
        int b = tid / SS, p = tid % SS;
        size_t idx = (size_t)(b * OC + oc) * SS + p;
        float mi = first ? 0.f : mem[idx];
        float mo;
        float val = lif_update(mi, tot, thr_v[layer], leak_v[layer], &mo);
        mem[idx] = mo;
        if (POOL) pvs[tid] = val;
        else out[idx] = val;
    }
    if (POOL) {
        __syncthreads();
        constexpr int Sh = S / 2, SSh = Sh * Sh;
        if (tid < 4 * SSh) {
            int b = tid / SSh, q = tid % SSh;
            int pr = q / Sh, pc = q % Sh;
            float pv = 0.25f * (pvs[b * SS + (2 * pr) * S + 2 * pc] +
                                pvs[b * SS + (2 * pr) * S + 2 * pc + 1] +
                                pvs[b * SS + (2 * pr + 1) * S + 2 * pc] +
                                pvs[b * SS + (2 * pr + 1) * S + 2 * pc + 1]);
            out[((size_t)(b * OC + oc) * Sh + pr) * Sh + pc] = pv;
        }
    }
}

// Wave-per-output-neuron FC+LIF (float4 K-split, 4-batch reuse).
__global__ void fc_lif_wave_kernel(const float* __restrict__ in,
                                   const float* __restrict__ w,
                                   float* __restrict__ mem,
                                   float* __restrict__ out,
                                   const float* __restrict__ thr_v,
                                   const float* __restrict__ leak_v,
                                   int layer, int Kd, int N, int first) {
    int wave = (blockIdx.x * blockDim.x + threadIdx.x) >> 6;
    int lane = threadIdx.x & 63;
    if (wave >= N) return;
    int j = wave;
    int K4 = Kd >> 2;
    const float4* wp = (const float4*)(w + (size_t)j * Kd);
    const float4* ip = (const float4*)in;
    float a0 = 0.f, a1 = 0.f, a2 = 0.f, a3 = 0.f;
    for (int k = lane; k < K4; k += 64) {
        float4 wv = wp[k];
        float4 v0 = ip[k];
        float4 v1 = ip[K4 + k];
        float4 v2 = ip[2 * K4 + k];
        float4 v3 = ip[3 * K4 + k];
        a0 = fmaf(wv.x, v0.x, fmaf(wv.y, v0.y, fmaf(wv.z, v0.z, fmaf(wv.w, v0.w, a0))));
        a1 = fmaf(wv.x, v1.x, fmaf(wv.y, v1.y, fmaf(wv.z, v1.z, fmaf(wv.w, v1.w, a1))));
        a2 = fmaf(wv.x, v2.x, fmaf(wv.y, v2.y, fmaf(wv.z, v2.z, fmaf(wv.w, v2.w, a2))));
        a3 = fmaf(wv.x, v3.x, fmaf(wv.y, v3.y, fmaf(wv.z, v3.z, fmaf(wv.w, v3.w, a3))));
    }
#pragma unroll
    for (int off = 32; off > 0; off >>= 1) {
        a0 += __shfl_xor(a0, off);
        a1 += __shfl_xor(a1, off);
        a2 += __shfl_xor(a2, off);
        a3 += __shfl_xor(a3, off);
    }
    if (lane == 0) {
        float thr = thr_v[layer], leak = leak_v[layer];
        float accv[4] = {a0, a1, a2, a3};
#pragma unroll
        for (int b = 0; b < BATCH; ++b) {
            float mi = first ? 0.f : mem[(size_t)b * N + j];
            float mo;
            float val = lif_update(mi, accv[b], thr, leak, &mo);
            mem[(size_t)b * N + j] = mo;
            out[(size_t)b * N + j] = val;
        }
    }
}

// One 64-thread block per (b, label). logits (+)= in[b,:] . w[l,:]
__global__ void fc2_acc_kernel(const float* __restrict__ in,
                               const float* __restrict__ w,
                               float* __restrict__ logits,
                               int Kd, int L, int init) {
    int o = blockIdx.x;
    int l = o % L;
    int b = o / L;
    int K4 = Kd >> 2;
    const float4* ip = (const float4*)(in + (size_t)b * Kd);
    const float4* wp = (const float4*)(w + (size_t)l * Kd);
    float s = 0.f;
    for (int k = threadIdx.x; k < K4; k += 64) {
        float4 iv = ip[k];
        float4 wv = wp[k];
        s = fmaf(iv.x, wv.x, fmaf(iv.y, wv.y, fmaf(iv.z, wv.z, fmaf(iv.w, wv.w, s))));
    }
#pragma unroll
    for (int off = 32; off > 0; off >>= 1) s += __shfl_xor(s, off);
    if (threadIdx.x == 0) logits[o] = init ? s : logits[o] + s;
}

extern "C" void kernel_launch(void* const* d_in, const int* in_sizes, int n_in,
                              void* d_out, int out_size, void* d_ws, size_t ws_size,
                              hipStream_t stream) {
    const float* x = (const float*)d_in[0];
    const float* convw[13];
    for (int i = 0; i < 13; ++i) convw[i] = (const float*)d_in[1 + i];
    const float* fc0 = (const float*)d_in[14];
    const float* fc1 = (const float*)d_in[15];
    const float* fc2 = (const float*)d_in[16];
    const float* thr = (const float*)d_in[17];
    const float* leak = (const float*)d_in[18];

    static const int IC[13] = {3, 64, 64, 128, 128, 256, 256, 256, 512, 512, 512, 512, 512};
    static const int OC[13] = {64, 64, 128, 128, 256, 256, 256, 512, 512, 512, 512, 512, 512};
    static const int HH[13] = {32, 32, 16, 16, 8, 8, 8, 4, 4, 4, 2, 2, 2};

    float* ws = (float*)d_ws;
    size_t off = 0;
    float* convmem[13];
    for (int i = 0; i < 13; ++i) {
        convmem[i] = ws + off;
        off += (size_t)BATCH * OC[i] * HH[i] * HH[i];
    }
    float* mfc0 = ws + off; off += BATCH * 4096;
    float* mfc1 = ws + off; off += BATCH * 4096;
    float* bufs[3];
    for (int i = 0; i < 3; ++i) { bufs[i] = ws + off; off += 262144; }

    for (int t = 0; t < 3; ++t) {
        int first = (t == 0);
        const float* src = x;
        int cur = -1;
        for (int i = 0; i < 13; ++i) {
            int d = (cur + 1) % 3;
            if (cur < 0) d = 0;
            int H = HH[i], W = HH[i];
            if (i == 0) {
                int n = BATCH * OC[i] * H * W;
                conv_lif_kernel<<<(n + 255) / 256, 256, 0, stream>>>(
                    src, convw[i], convmem[i], bufs[d], thr, leak, i,
                    IC[i], OC[i], H, W, n, first);
            } else if (i == 1) {
                // 64->64 @32x32, pool: OCT=8, NW=4
                int blocks = BATCH * (H * W / 64) * (OC[i] / 8);
                conv_mid_kernel<8, 4, 1><<<blocks, 256, 0, stream>>>(
                    src, convw[i], convmem[i], bufs[d], thr, leak, i,
                    IC[i], OC[i], H, W, first);
            } else if (i == 2) {
                int blocks = BATCH * (H * W / 64) * (OC[i] / 4);
                conv_mid_kernel<4, 4, 0><<<blocks, 256, 0, stream>>>(
                    src, convw[i], convmem[i], bufs[d], thr, leak, i,
                    IC[i], OC[i], H, W, first);
            } else if (i == 3) {
                int blocks = BATCH * (H * W / 64) * (OC[i] / 4);
                conv_mid_kernel<4, 8, 1><<<blocks, 512, 0, stream>>>(
                    src, convw[i], convmem[i], bufs[d], thr, leak, i,
                    IC[i], OC[i], H, W, first);
            } else if (i == 4 || i == 5) {
                int blocks = BATCH * (H * W / 64) * (OC[i] / 4);
                conv_mid_kernel<4, 8, 0><<<blocks, 512, 0, stream>>>(
                    src, convw[i], convmem[i], bufs[d], thr, leak, i,
                    IC[i], OC[i], H, W, first);
            } else if (i == 6) {
                int blocks = BATCH * (H * W / 64) * (OC[i] / 4);
                conv_mid_kernel<4, 8, 1><<<blocks, 512, 0, stream>>>(
                    src, convw[i], convmem[i], bufs[d], thr, leak, i,
                    IC[i], OC[i], H, W, first);
            } else if (i == 7 || i == 8) {
                conv_small4_kernel<4, 0><<<OC[i], 256, 0, stream>>>(
                    src, convw[i], convmem[i], bufs[d], thr, leak, i,
                    IC[i], OC[i], first);
            } else if (i == 9) {
                conv_small4_kernel<4, 1><<<OC[i], 256, 0, stream>>>(
                    src, convw[i], convmem[i], bufs[d], thr, leak, i,
                    IC[i], OC[i], first);
            } else {  // 10..12, 2x2
                conv_small4_kernel<2, 0><<<OC[i], 256, 0, stream>>>(
                    src, convw[i], convmem[i], bufs[d], thr, leak, i,
                    IC[i], OC[i], first);
            }
            cur = d; src = bufs[cur];
        }
        {
            int d = (cur + 1) % 3;
            fc_lif_wave_kernel<<<(4096 * 64) / 256, 256, 0, stream>>>(
                src, fc0, mfc0, bufs[d], thr, leak, 13, 2048, 4096, first);
            cur = d; src = bufs[cur];
        }
        {
            int d = (cur + 1) % 3;
            fc_lif_wave_kernel<<<(4096 * 64) / 256, 256, 0, stream>>>(
                src, fc1, mfc1, bufs[d], thr, leak, 14, 4096, 4096, first);
            cur = d; src = bufs[cur];
        }
        fc2_acc_kernel<<<BATCH * 10, 64, 0, stream>>>(
            src, fc2, (float*)d_out, 4096, 10, first);
    }
}